// Round 2
// baseline (563.540 us; speedup 1.0000x reference)
//
#include <hip/hip_runtime.h>

// SparseAutoEncoder: hypernetwork-generated per-sample MLP weights, fused.
// EN layers (rows in en_W2): (2000,200) lin @0, (200,100) tanh @400200, (100,10) lin @420300
// DE layers (rows in de_W2): (10,100) lin @0, (100,200) tanh @1100, (200,2000) lin @21300
// Hyper width K = 64, batch B = 64. h: (b,k) b-major. xT layouts: (i,b) i-major.
//
// fc_kernel design (R2): lane = k, wave = batch-quarter (acc[16] per lane, stays in
// VGPRs — R1's acc[64] spilled at VGPR_Count=52). All 4 waves scan all i of the
// chunk; W rows are shared via L1 so HBM traffic is still 1x. x comes in via
// wave-uniform scalar loads. No LDS reduction -> occupancy 8 blocks/CU.

// ---------------------------------------------------------------------------
// prep: transpose z (64x2000) -> zT (2000x64), and compute h_en, h_de (64x64)
// ---------------------------------------------------------------------------
__global__ __launch_bounds__(256) void prep_kernel(
    const float* __restrict__ z, const float* __restrict__ mu,
    const float* __restrict__ enW0, const float* __restrict__ enb0,
    const float* __restrict__ enW1, const float* __restrict__ enb1,
    const float* __restrict__ deW0, const float* __restrict__ deb0,
    const float* __restrict__ deW1, const float* __restrict__ deb1,
    float* __restrict__ zT, float* __restrict__ hen, float* __restrict__ hde)
{
    __shared__ float tile[64 * 65];
    __shared__ float h0s[4][64];
    const int bid  = blockIdx.x;
    const int lane = threadIdx.x & 63;
    const int g    = threadIdx.x >> 6;

    if (bid < 32) {
        // 64x64 tile transpose of z
        const int t0 = bid * 64;
        for (int bb = g; bb < 64; bb += 4) {
            int i = t0 + lane;
            tile[bb * 65 + lane] = (i < 2000) ? z[bb * 2000 + i] : 0.f;
        }
        __syncthreads();
        for (int ii = g; ii < 64; ii += 4) {
            int i = t0 + ii;
            if (i < 2000) zT[i * 64 + lane] = tile[lane * 65 + ii];
        }
    } else {
        // hypernetwork MLP: task = (which, b); lane = output neuron j
        const int task  = (bid - 32) * 4 + g;   // 0..127
        const int which = task >> 6;            // 0 = en, 1 = de
        const int b     = task & 63;
        const float* W0 = which ? deW0 : enW0;
        const float* b0 = which ? deb0 : enb0;
        const float* W1 = which ? deW1 : enW1;
        const float* b1 = which ? deb1 : enb1;
        float* hout     = which ? hde : hen;
        const int j = lane;
        float m0 = mu[b * 4 + 0], m1 = mu[b * 4 + 1], m2 = mu[b * 4 + 2], m3 = mu[b * 4 + 3];
        float v = tanhf(m0 * W0[j * 4 + 0] + m1 * W0[j * 4 + 1] +
                        m2 * W0[j * 4 + 2] + m3 * W0[j * 4 + 3] + b0[j]);
        h0s[g][j] = v;
        __syncthreads();
        float a = b1[j];
        const float* W1r = W1 + j * 64;
        #pragma unroll 8
        for (int k = 0; k < 64; ++k) a = fmaf(h0s[g][k], W1r[k], a);
        hout[b * 64 + j] = tanhf(a);
    }
}

// ---------------------------------------------------------------------------
// fused hyper-FC layer:
//   yT[o,b] = act( sum_k h[b,k]*(T[b,k]+Wbias[o,k]) + sum_i x[b,i]*b2[o*NI+i]
//                  + b2[NO*NI+o] ),   T[b,k] = sum_i xT[i,b]*W2[(o*NI+i),k]
// lane = k; wave = batch-quarter (16 accumulators/lane); i split across NSPLIT
// blocks (atomic combine, linear layers only).
// ---------------------------------------------------------------------------
template <int NI, int NO, int NSPLIT, bool TANH, bool ATOMIC>
__global__ __launch_bounds__(256) void fc_kernel(
    const float* __restrict__ xT,   // NI x 64 (i-major)
    const float* __restrict__ h,    // 64 x 64 (b-major)
    const float* __restrict__ W2,   // layer base, (NO*NI+NO) x 64
    const float* __restrict__ b2,   // layer base, NO*NI+NO
    float* __restrict__ yT)         // NO x 64
{
    __shared__ float xbs[64];
    const int lane = threadIdx.x & 63;
    const int wave = __builtin_amdgcn_readfirstlane(threadIdx.x >> 6);
    const int o = blockIdx.x / NSPLIT;
    const int s = blockIdx.x - o * NSPLIT;
    constexpr int CH = NI / NSPLIT;      // NI divisible by NSPLIT
    const int i0 = s * CH;

    const float* __restrict__ Wp  = W2 + ((size_t)o * NI + i0) * 64 + lane;
    const float* __restrict__ xp  = xT + i0 * 64;
    const float* __restrict__ b2w = b2 + (size_t)o * NI + i0;

    float acc[16];
    #pragma unroll
    for (int j = 0; j < 16; ++j) acc[j] = 0.f;
    float xb_acc = 0.f;

    // main loop: all waves scan all i; wave-uniform x via scalar loads
    #pragma unroll 4
    for (int i = 0; i < CH; ++i) {
        float w = Wp[(size_t)i * 64];                      // coalesced, streamed (vmcnt pipelined)
        if (wave == 0)                                     // bias-dot, one wave only
            xb_acc = fmaf(xp[i * 64 + lane], b2w[i], xb_acc);
        const float4* xr = (const float4*)(xp + i * 64 + wave * 16);  // uniform -> s_load
        float4 x0 = xr[0], x1 = xr[1], x2 = xr[2], x3 = xr[3];
        acc[ 0] = fmaf(x0.x, w, acc[ 0]);
        acc[ 1] = fmaf(x0.y, w, acc[ 1]);
        acc[ 2] = fmaf(x0.z, w, acc[ 2]);
        acc[ 3] = fmaf(x0.w, w, acc[ 3]);
        acc[ 4] = fmaf(x1.x, w, acc[ 4]);
        acc[ 5] = fmaf(x1.y, w, acc[ 5]);
        acc[ 6] = fmaf(x1.z, w, acc[ 6]);
        acc[ 7] = fmaf(x1.w, w, acc[ 7]);
        acc[ 8] = fmaf(x2.x, w, acc[ 8]);
        acc[ 9] = fmaf(x2.y, w, acc[ 9]);
        acc[10] = fmaf(x2.z, w, acc[10]);
        acc[11] = fmaf(x2.w, w, acc[11]);
        acc[12] = fmaf(x3.x, w, acc[12]);
        acc[13] = fmaf(x3.y, w, acc[13]);
        acc[14] = fmaf(x3.z, w, acc[14]);
        acc[15] = fmaf(x3.w, w, acc[15]);
    }

    if (wave == 0) xbs[lane] = xb_acc;

    // epilogue: k-contraction with h; butterfly over 64 lanes per b
    float wb = 0.f;
    if (!ATOMIC || s == 0) wb = W2[((size_t)NO * NI + o) * 64 + lane];
    float myv = 0.f;
    #pragma unroll
    for (int j = 0; j < 16; ++j) {
        int b = wave * 16 + j;
        float v = (acc[j] + wb) * h[b * 64 + lane];
        #pragma unroll
        for (int m = 32; m >= 1; m >>= 1) v += __shfl_xor(v, m, 64);
        if (lane == j) myv = v;
    }
    __syncthreads();
    if (lane < 16) {
        int b = wave * 16 + lane;
        float out = myv + xbs[b];
        if (!ATOMIC || s == 0) out += b2[(size_t)NO * NI + o];
        if (TANH) out = tanhf(out);
        if (ATOMIC) atomicAdd(&yT[o * 64 + b], out);
        else        yT[o * 64 + b] = out;
    }
}

// ---------------------------------------------------------------------------
// finalize: d_out = [ z_reconst (64x2000 b-major) , x_enc (64x10 b-major) ]
// ---------------------------------------------------------------------------
__global__ __launch_bounds__(256) void final_kernel(
    const float* __restrict__ d3,   // 2000 x 64 (o-major)
    const float* __restrict__ y3,   // 10 x 64 (o-major)
    float* __restrict__ out)
{
    int t = blockIdx.x * 256 + threadIdx.x;
    if (t < 128000) {
        int b = t / 2000, oo = t - b * 2000;
        out[t] = d3[oo * 64 + b];
    } else if (t < 128640) {
        int u = t - 128000;
        int b = u / 10, oo = u - b * 10;
        out[t] = y3[oo * 64 + b];
    }
}

extern "C" void kernel_launch(void* const* d_in, const int* in_sizes, int n_in,
                              void* d_out, int out_size, void* d_ws, size_t ws_size,
                              hipStream_t stream)
{
    const float* z    = (const float*)d_in[0];
    const float* mu   = (const float*)d_in[1];
    const float* enW0 = (const float*)d_in[2];
    const float* enb0 = (const float*)d_in[3];
    const float* enW1 = (const float*)d_in[4];
    const float* enb1 = (const float*)d_in[5];
    const float* enW2 = (const float*)d_in[6];
    const float* enb2 = (const float*)d_in[7];
    const float* deW0 = (const float*)d_in[8];
    const float* deb0 = (const float*)d_in[9];
    const float* deW1 = (const float*)d_in[10];
    const float* deb1 = (const float*)d_in[11];
    const float* deW2 = (const float*)d_in[12];
    const float* deb2 = (const float*)d_in[13];

    float* ws  = (float*)d_ws;
    float* zT  = ws;                 // 2000*64
    float* hen = zT + 128000;        // 64*64
    float* hde = hen + 4096;         // 64*64
    float* y1  = hde + 4096;         // 200*64  (atomic target -> zeroed)
    float* y2  = y1 + 200 * 64;      // 100*64
    float* y3  = y2 + 100 * 64;      // 10*64   (x_enc, transposed)
    float* d1  = y3 + 10 * 64;       // 100*64
    float* d2  = d1 + 100 * 64;      // 200*64
    float* d3  = d2 + 200 * 64;      // 2000*64
    float* out = (float*)d_out;

    hipMemsetAsync(y1, 0, 200 * 64 * sizeof(float), stream);
    prep_kernel<<<64, 256, 0, stream>>>(z, mu, enW0, enb0, enW1, enb1,
                                        deW0, deb0, deW1, deb1, zT, hen, hde);
    // encoder
    fc_kernel<2000, 200, 10, false, true ><<<2000, 256, 0, stream>>>(zT, hen, enW2, enb2, y1);
    fc_kernel< 200, 100,  1, true,  false><<< 100, 256, 0, stream>>>(y1, hen, enW2 + (size_t)400200 * 64, enb2 + 400200, y2);
    fc_kernel< 100,  10,  1, false, false><<<  10, 256, 0, stream>>>(y2, hen, enW2 + (size_t)420300 * 64, enb2 + 420300, y3);
    // decoder
    fc_kernel<  10, 100,  1, false, false><<< 100, 256, 0, stream>>>(y3, hde, deW2, deb2, d1);
    fc_kernel< 100, 200,  1, true,  false><<< 200, 256, 0, stream>>>(d1, hde, deW2 + (size_t)1100 * 64, deb2 + 1100, d2);
    fc_kernel< 200, 2000, 1, false, false><<<2000, 256, 0, stream>>>(d2, hde, deW2 + (size_t)21300 * 64, deb2 + 21300, d3);

    final_kernel<<<(128640 + 255) / 256, 256, 0, stream>>>(d3, y3, out);
}

// Round 3
// 518.116 us; speedup vs baseline: 1.0877x; 1.0877x over previous
//
#include <hip/hip_runtime.h>

// SparseAutoEncoder: hypernetwork-generated per-sample MLP weights, fused.
// EN layers (rows in en_W2): (2000,200) lin @0, (200,100) tanh @400200, (100,10) lin @420300
// DE layers (rows in de_W2): (10,100) lin @0, (100,200) tanh @1100, (200,2000) lin @21300
// Hyper width K = 64, batch B = 64. h: (b,k) b-major. xT layouts: (i,b) i-major.
//
// R3: x broadcast via LDS (ds_read is in-order -> fine-grained lgkmcnt, pipelines
// with fma), NOT via wave-uniform s_load (SMEM is out-of-order -> lgkmcnt(0) drain
// per iteration, which serialized R2 to VALUBusy 17%). lane = k, wave = batch
// quarter, acc[16] in VGPRs.

// ---------------------------------------------------------------------------
// prep: transpose z (64x2000) -> zT (2000x64), and compute h_en, h_de (64x64)
// ---------------------------------------------------------------------------
__global__ __launch_bounds__(256) void prep_kernel(
    const float* __restrict__ z, const float* __restrict__ mu,
    const float* __restrict__ enW0, const float* __restrict__ enb0,
    const float* __restrict__ enW1, const float* __restrict__ enb1,
    const float* __restrict__ deW0, const float* __restrict__ deb0,
    const float* __restrict__ deW1, const float* __restrict__ deb1,
    float* __restrict__ zT, float* __restrict__ hen, float* __restrict__ hde)
{
    __shared__ float tile[64 * 65];
    __shared__ float h0s[4][64];
    const int bid  = blockIdx.x;
    const int lane = threadIdx.x & 63;
    const int g    = threadIdx.x >> 6;

    if (bid < 32) {
        const int t0 = bid * 64;
        for (int bb = g; bb < 64; bb += 4) {
            int i = t0 + lane;
            tile[bb * 65 + lane] = (i < 2000) ? z[bb * 2000 + i] : 0.f;
        }
        __syncthreads();
        for (int ii = g; ii < 64; ii += 4) {
            int i = t0 + ii;
            if (i < 2000) zT[i * 64 + lane] = tile[lane * 65 + ii];
        }
    } else {
        const int task  = (bid - 32) * 4 + g;   // 0..127
        const int which = task >> 6;            // 0 = en, 1 = de
        const int b     = task & 63;
        const float* W0 = which ? deW0 : enW0;
        const float* b0 = which ? deb0 : enb0;
        const float* W1 = which ? deW1 : enW1;
        const float* b1 = which ? deb1 : enb1;
        float* hout     = which ? hde : hen;
        const int j = lane;
        float m0 = mu[b * 4 + 0], m1 = mu[b * 4 + 1], m2 = mu[b * 4 + 2], m3 = mu[b * 4 + 3];
        float v = tanhf(m0 * W0[j * 4 + 0] + m1 * W0[j * 4 + 1] +
                        m2 * W0[j * 4 + 2] + m3 * W0[j * 4 + 3] + b0[j]);
        h0s[g][j] = v;
        __syncthreads();
        float a = b1[j];
        const float* W1r = W1 + j * 64;
        #pragma unroll 8
        for (int k = 0; k < 64; ++k) a = fmaf(h0s[g][k], W1r[k], a);
        hout[b * 64 + j] = tanhf(a);
    }
}

// ---------------------------------------------------------------------------
// fused hyper-FC layer:
//   yT[o,b] = act( sum_k h[b,k]*(T[b,k]+Wbias[o,k]) + sum_i x[b,i]*b2[o*NI+i]
//                  + b2[NO*NI+o] ),   T[b,k] = sum_i xT[i,b]*W2[(o*NI+i),k]
// lane = k; wave = batch-quarter (acc[16] in VGPRs); x chunk staged in LDS,
// broadcast via uniform ds_read_b128 (conflict-free, in-order).
// i split across NSPLIT blocks (atomic combine, linear layers only).
// ---------------------------------------------------------------------------
template <int NI, int NO, int NSPLIT, bool TANH, bool ATOMIC>
__global__ __launch_bounds__(256) void fc_kernel(
    const float* __restrict__ xT,   // NI x 64 (i-major)
    const float* __restrict__ h,    // 64 x 64 (b-major)
    const float* __restrict__ W2,   // layer base, (NO*NI+NO) x 64
    const float* __restrict__ b2,   // layer base, NO*NI+NO
    float* __restrict__ yT)         // NO x 64
{
    constexpr int CH = NI / NSPLIT;          // NI divisible by NSPLIT
    __shared__ __align__(16) float xs[CH * 64];
    __shared__ float b2s[CH];
    __shared__ float xbs[64];
    const int lane = threadIdx.x & 63;
    const int wave = threadIdx.x >> 6;
    const int o = blockIdx.x / NSPLIT;
    const int s = blockIdx.x - o * NSPLIT;
    const int i0 = s * CH;

    // stage x chunk + b2 chunk into LDS (one-time)
    {
        const float4* __restrict__ src = (const float4*)(xT + i0 * 64);
        float4* dst = (float4*)xs;
        for (int u = threadIdx.x; u < CH * 16; u += 256) dst[u] = src[u];
        const float* __restrict__ bsrc = b2 + (size_t)o * NI + i0;
        for (int u = threadIdx.x; u < CH; u += 256) b2s[u] = bsrc[u];
    }
    __syncthreads();

    const float* __restrict__ Wp = W2 + ((size_t)o * NI + i0) * 64 + lane;

    float acc[16];
    #pragma unroll
    for (int j = 0; j < 16; ++j) acc[j] = 0.f;
    float xb_acc = 0.f;

    #pragma unroll 4
    for (int i = 0; i < CH; ++i) {
        float w = Wp[(size_t)i * 64];            // coalesced 256B/wave, streamed
        if (wave == 0)                           // bias-dot on wave 0 only
            xb_acc = fmaf(xs[i * 64 + lane], b2s[i], xb_acc);
        const float4* xr = (const float4*)(xs + i * 64 + wave * 16);  // uniform -> broadcast
        float4 x0 = xr[0], x1 = xr[1], x2 = xr[2], x3 = xr[3];
        acc[ 0] = fmaf(x0.x, w, acc[ 0]);
        acc[ 1] = fmaf(x0.y, w, acc[ 1]);
        acc[ 2] = fmaf(x0.z, w, acc[ 2]);
        acc[ 3] = fmaf(x0.w, w, acc[ 3]);
        acc[ 4] = fmaf(x1.x, w, acc[ 4]);
        acc[ 5] = fmaf(x1.y, w, acc[ 5]);
        acc[ 6] = fmaf(x1.z, w, acc[ 6]);
        acc[ 7] = fmaf(x1.w, w, acc[ 7]);
        acc[ 8] = fmaf(x2.x, w, acc[ 8]);
        acc[ 9] = fmaf(x2.y, w, acc[ 9]);
        acc[10] = fmaf(x2.z, w, acc[10]);
        acc[11] = fmaf(x2.w, w, acc[11]);
        acc[12] = fmaf(x3.x, w, acc[12]);
        acc[13] = fmaf(x3.y, w, acc[13]);
        acc[14] = fmaf(x3.z, w, acc[14]);
        acc[15] = fmaf(x3.w, w, acc[15]);
    }

    if (wave == 0) xbs[lane] = xb_acc;

    // epilogue: k-contraction with h; butterfly over 64 lanes per b
    float wb = 0.f;
    if (!ATOMIC || s == 0) wb = W2[((size_t)NO * NI + o) * 64 + lane];
    float myv = 0.f;
    #pragma unroll
    for (int j = 0; j < 16; ++j) {
        int b = wave * 16 + j;
        float v = (acc[j] + wb) * h[b * 64 + lane];
        #pragma unroll
        for (int m = 32; m >= 1; m >>= 1) v += __shfl_xor(v, m, 64);
        if (lane == j) myv = v;
    }
    __syncthreads();
    if (lane < 16) {
        int b = wave * 16 + lane;
        float out = myv + xbs[b];
        if (!ATOMIC || s == 0) out += b2[(size_t)NO * NI + o];
        if (TANH) out = tanhf(out);
        if (ATOMIC) atomicAdd(&yT[o * 64 + b], out);
        else        yT[o * 64 + b] = out;
    }
}

// ---------------------------------------------------------------------------
// finalize: d_out = [ z_reconst (64x2000 b-major) , x_enc (64x10 b-major) ]
// ---------------------------------------------------------------------------
__global__ __launch_bounds__(256) void final_kernel(
    const float* __restrict__ d3,   // 2000 x 64 (o-major)
    const float* __restrict__ y3,   // 10 x 64 (o-major)
    float* __restrict__ out)
{
    int t = blockIdx.x * 256 + threadIdx.x;
    if (t < 128000) {
        int b = t / 2000, oo = t - b * 2000;
        out[t] = d3[oo * 64 + b];
    } else if (t < 128640) {
        int u = t - 128000;
        int b = u / 10, oo = u - b * 10;
        out[t] = y3[oo * 64 + b];
    }
}

extern "C" void kernel_launch(void* const* d_in, const int* in_sizes, int n_in,
                              void* d_out, int out_size, void* d_ws, size_t ws_size,
                              hipStream_t stream)
{
    const float* z    = (const float*)d_in[0];
    const float* mu   = (const float*)d_in[1];
    const float* enW0 = (const float*)d_in[2];
    const float* enb0 = (const float*)d_in[3];
    const float* enW1 = (const float*)d_in[4];
    const float* enb1 = (const float*)d_in[5];
    const float* enW2 = (const float*)d_in[6];
    const float* enb2 = (const float*)d_in[7];
    const float* deW0 = (const float*)d_in[8];
    const float* deb0 = (const float*)d_in[9];
    const float* deW1 = (const float*)d_in[10];
    const float* deb1 = (const float*)d_in[11];
    const float* deW2 = (const float*)d_in[12];
    const float* deb2 = (const float*)d_in[13];

    float* ws  = (float*)d_ws;
    float* zT  = ws;                 // 2000*64
    float* hen = zT + 128000;        // 64*64
    float* hde = hen + 4096;         // 64*64
    float* y1  = hde + 4096;         // 200*64  (atomic target -> zeroed)
    float* y2  = y1 + 200 * 64;      // 100*64
    float* y3  = y2 + 100 * 64;      // 10*64   (x_enc, transposed)
    float* d1  = y3 + 10 * 64;       // 100*64
    float* d2  = d1 + 100 * 64;      // 200*64
    float* d3  = d2 + 200 * 64;      // 2000*64 (atomic target -> zeroed)
    float* out = (float*)d_out;

    hipMemsetAsync(y1, 0, 200 * 64 * sizeof(float), stream);
    hipMemsetAsync(d3, 0, 2000 * 64 * sizeof(float), stream);
    prep_kernel<<<64, 256, 0, stream>>>(z, mu, enW0, enb0, enW1, enb1,
                                        deW0, deb0, deW1, deb1, zT, hen, hde);
    // encoder
    fc_kernel<2000, 200, 16, false, true ><<<3200, 256, 0, stream>>>(zT, hen, enW2, enb2, y1);
    fc_kernel< 200, 100,  1, true,  false><<< 100, 256, 0, stream>>>(y1, hen, enW2 + (size_t)400200 * 64, enb2 + 400200, y2);
    fc_kernel< 100,  10,  1, false, false><<<  10, 256, 0, stream>>>(y2, hen, enW2 + (size_t)420300 * 64, enb2 + 420300, y3);
    // decoder
    fc_kernel<  10, 100,  1, false, false><<< 100, 256, 0, stream>>>(y3, hde, deW2, deb2, d1);
    fc_kernel< 100, 200,  1, true,  false><<< 200, 256, 0, stream>>>(d1, hde, deW2 + (size_t)1100 * 64, deb2 + 1100, d2);
    fc_kernel< 200, 2000, 2, false, true ><<<4000, 256, 0, stream>>>(d2, hde, deW2 + (size_t)21300 * 64, deb2 + 21300, d3);

    final_kernel<<<(128640 + 255) / 256, 256, 0, stream>>>(d3, y3, out);
}